// Round 1
// baseline (5567.575 us; speedup 1.0000x reference)
//
#include <hip/hip_runtime.h>
#include <hip/hip_bf16.h>
#include <math.h>

#define B_      32
#define H_      56
#define W_      56
#define C_      384
#define HEADS_  12
#define WIN_    7
#define SHIFT_  3
#define NTOK_   49
#define HD_     32
#define T_      100352   // B_*H_*W_
#define MLP_    1536

__device__ __forceinline__ float bf2f(unsigned short u) {
  union { unsigned int i; float f; } v; v.i = ((unsigned int)u) << 16; return v.f;
}
__device__ __forceinline__ unsigned short f2bf(float f) {
  union { float f; unsigned int i; } v; v.f = f;
  unsigned int x = v.i;
  return (unsigned short)((x + 0x7fffu + ((x >> 16) & 1u)) >> 16);
}
__device__ __forceinline__ float gelu_exact(float x) {
  return 0.5f * x * (1.0f + erff(x * 0.7071067811865475f));
}

// ---------------- LayerNorm (optionally fused shift+window-partition remap) --
// REMAP=1: block m = window-layout token; source row = roll(-3,-3) location.
// REMAP=0: identity rows (for LN2 on x1).
template<int REMAP>
__global__ __launch_bounds__(64)
void ln_kernel(const float* __restrict__ xin, const float* __restrict__ g,
               const float* __restrict__ bb, unsigned short* __restrict__ outbf) {
  const int m = blockIdx.x;
  const int lane = threadIdx.x;
  size_t src;
  if (REMAP) {
    int w = m / NTOK_, t = m - w * NTOK_;
    int bz = w >> 6, widx = w & 63;
    int wh = widx >> 3, ww = widx & 7;
    int ih = t / WIN_, iw = t - ih * WIN_;
    int gh = (wh * WIN_ + ih + SHIFT_) % H_;
    int gw = (ww * WIN_ + iw + SHIFT_) % W_;
    src = ((size_t)bz * (H_ * W_) + gh * W_ + gw) * C_;
  } else {
    src = (size_t)m * C_;
  }
  const float* row = xin + src;
  float v[6]; float s = 0.f, s2 = 0.f;
#pragma unroll
  for (int u = 0; u < 6; ++u) {
    v[u] = row[lane + 64 * u];
    s += v[u]; s2 += v[u] * v[u];
  }
#pragma unroll
  for (int off = 32; off; off >>= 1) {
    s  += __shfl_xor(s, off);
    s2 += __shfl_xor(s2, off);
  }
  const float mean = s * (1.0f / C_);
  const float var  = s2 * (1.0f / C_) - mean * mean;
  const float rstd = rsqrtf(var + 1e-5f);
  unsigned short* orow = outbf + (size_t)m * C_;
#pragma unroll
  for (int u = 0; u < 6; ++u) {
    int c = lane + 64 * u;
    orow[c] = f2bf((v[u] - mean) * rstd * g[c] + bb[c]);
  }
}

// ---------------- Tiled GEMM: C[M,N] = A[M,K](bf16) @ Wt[N,K]^T(f32) + bias --
// EPI: 0 = store bf16; 1 = gelu->bf16; 2 = window-reverse+unshift + resid ->f32 d_out;
//      3 = d_out[m,n] += val (f32, d_out already holds x1)
#define BM 64
#define BN 64
#define BK 16

template<int EPI>
__global__ __launch_bounds__(256)
void gemm_kernel(const unsigned short* __restrict__ A,
                 const float* __restrict__ Wt,
                 const float* __restrict__ bias,
                 void* __restrict__ outv,
                 const float* __restrict__ resid,
                 int M, int Nn, int K) {
  __shared__ float As[BK][BM + 4];
  __shared__ float Bs[BK][BN + 4];
  const int t  = threadIdx.x;
  const int m0 = blockIdx.y * BM;
  const int n0 = blockIdx.x * BN;
  const int lrow = t >> 2;   // 0..63
  const int kq   = t & 3;    // 0..3
  const int ty   = t >> 4;   // 0..15
  const int tx   = t & 15;
  float acc[4][4] = {};

  const unsigned short* aptr = A  + (size_t)(m0 + lrow) * K + kq * 4;
  const float*          wptr = Wt + (size_t)(n0 + lrow) * K + kq * 4;

  for (int k0 = 0; k0 < K; k0 += BK) {
    const ushort4 av = *(const ushort4*)(aptr + k0);
    const float4  wv = *(const float4*)(wptr + k0);
    __syncthreads();
    As[kq * 4 + 0][lrow] = bf2f(av.x);
    As[kq * 4 + 1][lrow] = bf2f(av.y);
    As[kq * 4 + 2][lrow] = bf2f(av.z);
    As[kq * 4 + 3][lrow] = bf2f(av.w);
    Bs[kq * 4 + 0][lrow] = wv.x;
    Bs[kq * 4 + 1][lrow] = wv.y;
    Bs[kq * 4 + 2][lrow] = wv.z;
    Bs[kq * 4 + 3][lrow] = wv.w;
    __syncthreads();
#pragma unroll
    for (int k = 0; k < BK; ++k) {
      const float4 a = *(const float4*)&As[k][ty * 4];
      const float4 b = *(const float4*)&Bs[k][tx * 4];
      acc[0][0] += a.x * b.x; acc[0][1] += a.x * b.y; acc[0][2] += a.x * b.z; acc[0][3] += a.x * b.w;
      acc[1][0] += a.y * b.x; acc[1][1] += a.y * b.y; acc[1][2] += a.y * b.z; acc[1][3] += a.y * b.w;
      acc[2][0] += a.z * b.x; acc[2][1] += a.z * b.y; acc[2][2] += a.z * b.z; acc[2][3] += a.z * b.w;
      acc[3][0] += a.w * b.x; acc[3][1] += a.w * b.y; acc[3][2] += a.w * b.z; acc[3][3] += a.w * b.w;
    }
  }

#pragma unroll
  for (int i = 0; i < 4; ++i) {
    const int m = m0 + ty * 4 + i;
    size_t dstbase = 0;
    if (EPI == 2) {
      int w = m / NTOK_, tt = m - w * NTOK_;
      int bz = w >> 6, widx = w & 63;
      int wh = widx >> 3, ww = widx & 7;
      int ih = tt / WIN_, iw = tt - ih * WIN_;
      int gh = (wh * WIN_ + ih + SHIFT_) % H_;
      int gw = (ww * WIN_ + iw + SHIFT_) % W_;
      dstbase = ((size_t)bz * (H_ * W_) + gh * W_ + gw) * C_;
    }
#pragma unroll
    for (int j = 0; j < 4; ++j) {
      const int n = n0 + tx * 4 + j;
      float val = acc[i][j] + bias[n];
      if (EPI == 0) {
        ((unsigned short*)outv)[(size_t)m * Nn + n] = f2bf(val);
      } else if (EPI == 1) {
        ((unsigned short*)outv)[(size_t)m * Nn + n] = f2bf(gelu_exact(val));
      } else if (EPI == 2) {
        ((float*)outv)[dstbase + n] = resid[dstbase + n] + val;
      } else {
        float* o = (float*)outv + (size_t)m * Nn + n;
        *o += val;
      }
    }
  }
}

// ---------------- Windowed attention: one block = (window, head) ------------
__global__ __launch_bounds__(64)
void attn_kernel(const unsigned short* __restrict__ qkv,   // [T_,1152] bf16
                 const float* __restrict__ rel_bias,       // [169,12]
                 unsigned short* __restrict__ out) {       // [T_,384] bf16
  __shared__ float sQ[NTOK_][HD_];
  __shared__ float sK[NTOK_][HD_];
  __shared__ float sV[NTOK_][HD_];
  __shared__ float sS[NTOK_][NTOK_];
  const int blk  = blockIdx.x;
  const int w    = blk / HEADS_;
  const int head = blk - w * HEADS_;
  const int widx = w & 63;
  const int wh   = widx >> 3, ww = widx & 7;
  const bool edge = (wh == 7) || (ww == 7);
  const int lane = threadIdx.x;
  const size_t base = (size_t)w * NTOK_ * (3 * C_);

  for (int idx = lane; idx < NTOK_ * HD_; idx += 64) {
    int i = idx >> 5, d = idx & 31;
    size_t roff = base + (size_t)i * (3 * C_) + head * HD_ + d;
    sQ[i][d] = bf2f(qkv[roff])            * 0.17677669529663687f;  // 1/sqrt(32)
    sK[i][d] = bf2f(qkv[roff + C_]);
    sV[i][d] = bf2f(qkv[roff + 2 * C_]);
  }
  __syncthreads();

  for (int idx = lane; idx < NTOK_ * NTOK_; idx += 64) {
    int i = idx / NTOK_, j = idx - i * NTOK_;
    float s = 0.f;
#pragma unroll
    for (int d = 0; d < HD_; ++d) s += sQ[i][d] * sK[j][d];
    int ih = i / WIN_, iw = i - ih * WIN_;
    int jh = j / WIN_, jw = j - jh * WIN_;
    int ridx = (ih - jh + WIN_ - 1) * (2 * WIN_ - 1) + (iw - jw + WIN_ - 1);
    s += rel_bias[ridx * HEADS_ + head];
    if (edge) {
      int shi = wh * WIN_ + ih, swi = ww * WIN_ + iw;
      int shj = wh * WIN_ + jh, swj = ww * WIN_ + jw;
      int li = (shi < 49 ? 0 : (shi < 53 ? 1 : 2)) * 3 + (swi < 49 ? 0 : (swi < 53 ? 1 : 2));
      int lj = (shj < 49 ? 0 : (shj < 53 ? 1 : 2)) * 3 + (swj < 49 ? 0 : (swj < 53 ? 1 : 2));
      if (li != lj) s -= 100.0f;
    }
    sS[i][j] = s;
  }
  __syncthreads();

  if (lane < NTOK_) {
    float mx = -1e30f;
    for (int j = 0; j < NTOK_; ++j) mx = fmaxf(mx, sS[lane][j]);
    float sum = 0.f;
    for (int j = 0; j < NTOK_; ++j) { float e = expf(sS[lane][j] - mx); sS[lane][j] = e; sum += e; }
    float inv = 1.0f / sum;
    for (int j = 0; j < NTOK_; ++j) sS[lane][j] *= inv;
  }
  __syncthreads();

  for (int idx = lane; idx < NTOK_ * HD_; idx += 64) {
    int i = idx >> 5, d = idx & 31;
    float o = 0.f;
    for (int j = 0; j < NTOK_; ++j) o += sS[i][j] * sV[j][d];
    out[(size_t)(w * NTOK_ + i) * C_ + head * HD_ + d] = f2bf(o);
  }
}

// -----------------------------------------------------------------------------
extern "C" void kernel_launch(void* const* d_in, const int* in_sizes, int n_in,
                              void* d_out, int out_size, void* d_ws, size_t ws_size,
                              hipStream_t stream) {
  const float* x        = (const float*)d_in[0];
  const float* g1       = (const float*)d_in[1];
  const float* b1       = (const float*)d_in[2];
  const float* qkv_w    = (const float*)d_in[3];
  const float* qkv_b    = (const float*)d_in[4];
  const float* rel_bias = (const float*)d_in[5];
  const float* proj_w   = (const float*)d_in[6];
  const float* proj_b   = (const float*)d_in[7];
  const float* g2       = (const float*)d_in[8];
  const float* b2       = (const float*)d_in[9];
  const float* fc1_w    = (const float*)d_in[10];
  const float* fc1_b    = (const float*)d_in[11];
  const float* fc2_w    = (const float*)d_in[12];
  const float* fc2_b    = (const float*)d_in[13];
  float* out = (float*)d_out;

  char* ws = (char*)d_ws;
  // region A [0, 77,070,336): xw -> attn_out -> h2   (T_*384 bf16)
  // region B [77,070,336, ...): qkv (T_*1152 bf16 = 231,211,008) -> hid (T_*1536 bf16 = 308,281,344)
  unsigned short* xw   = (unsigned short*)(ws);
  unsigned short* qkvb = (unsigned short*)(ws + 77070336);
  unsigned short* attn_out = xw;    // reuse after QKV GEMM consumed xw
  unsigned short* h2   = xw;        // reuse after proj consumed attn_out
  unsigned short* hid  = qkvb;      // reuse after attention consumed qkv

  // 1. LN1 + shift + window partition -> xw (bf16, window layout)
  ln_kernel<1><<<dim3(T_), dim3(64), 0, stream>>>(x, g1, b1, xw);

  // 2. QKV GEMM: [T_,384] @ [1152,384]^T -> qkv (bf16)
  gemm_kernel<0><<<dim3(1152 / BN, T_ / BM), dim3(256), 0, stream>>>(
      xw, qkv_w, qkv_b, (void*)qkvb, nullptr, T_, 1152, 384);

  // 3. Windowed attention (bias + shift mask + softmax + PV) -> attn_out
  attn_kernel<<<dim3((T_ / NTOK_) * HEADS_), dim3(64), 0, stream>>>(qkvb, rel_bias, attn_out);

  // 4. proj GEMM + window-reverse + unshift + residual -> d_out = x1 (f32)
  gemm_kernel<2><<<dim3(384 / BN, T_ / BM), dim3(256), 0, stream>>>(
      attn_out, proj_w, proj_b, (void*)out, x, T_, 384, 384);

  // 5. LN2 on x1 -> h2 (bf16)
  ln_kernel<0><<<dim3(T_), dim3(64), 0, stream>>>(out, g2, b2, h2);

  // 6. FC1 + exact GELU -> hid (bf16)
  gemm_kernel<1><<<dim3(MLP_ / BN, T_ / BM), dim3(256), 0, stream>>>(
      h2, fc1_w, fc1_b, (void*)hid, nullptr, T_, MLP_, 384);

  // 7. FC2, d_out += result  (final = x1 + mlp)
  gemm_kernel<3><<<dim3(384 / BN, T_ / BM), dim3(256), 0, stream>>>(
      hid, fc2_w, fc2_b, (void*)out, nullptr, T_, 384, MLP_);
}

// Round 2
// 1738.426 us; speedup vs baseline: 3.2027x; 3.2027x over previous
//
#include <hip/hip_runtime.h>
#include <hip/hip_bf16.h>
#include <math.h>

#define B_      32
#define H_      56
#define W_      56
#define C_      384
#define HEADS_  12
#define WIN_    7
#define SHIFT_  3
#define NTOK_   49
#define HD_     32
#define T_      100352   // B_*H_*W_
#define MLP_    1536

typedef __bf16 bf16x8 __attribute__((ext_vector_type(8)));
typedef float  f32x4  __attribute__((ext_vector_type(4)));

__device__ __forceinline__ float bf2f(unsigned short u) {
  union { unsigned int i; float f; } v; v.i = ((unsigned int)u) << 16; return v.f;
}
__device__ __forceinline__ unsigned short f2bf(float f) {
  union { float f; unsigned int i; } v; v.f = f;
  unsigned int x = v.i;
  return (unsigned short)((x + 0x7fffu + ((x >> 16) & 1u)) >> 16);
}
__device__ __forceinline__ float gelu_exact(float x) {
  return 0.5f * x * (1.0f + erff(x * 0.7071067811865475f));
}
__device__ __forceinline__ void gload_lds16(const void* g, void* l) {
  __builtin_amdgcn_global_load_lds(
      (const __attribute__((address_space(1))) void*)g,
      (__attribute__((address_space(3))) void*)l, 16, 0, 0);
}

// ---------------- LayerNorm (optionally fused shift+window-partition remap) --
template<int REMAP>
__global__ __launch_bounds__(64)
void ln_kernel(const float* __restrict__ xin, const float* __restrict__ g,
               const float* __restrict__ bb, unsigned short* __restrict__ outbf) {
  const int m = blockIdx.x;
  const int lane = threadIdx.x;
  size_t src;
  if (REMAP) {
    int w = m / NTOK_, t = m - w * NTOK_;
    int bz = w >> 6, widx = w & 63;
    int wh = widx >> 3, ww = widx & 7;
    int ih = t / WIN_, iw = t - ih * WIN_;
    int gh = (wh * WIN_ + ih + SHIFT_) % H_;
    int gw = (ww * WIN_ + iw + SHIFT_) % W_;
    src = ((size_t)bz * (H_ * W_) + gh * W_ + gw) * C_;
  } else {
    src = (size_t)m * C_;
  }
  const float* row = xin + src;
  float v[6]; float s = 0.f, s2 = 0.f;
#pragma unroll
  for (int u = 0; u < 6; ++u) {
    v[u] = row[lane + 64 * u];
    s += v[u]; s2 += v[u] * v[u];
  }
#pragma unroll
  for (int off = 32; off; off >>= 1) {
    s  += __shfl_xor(s, off);
    s2 += __shfl_xor(s2, off);
  }
  const float mean = s * (1.0f / C_);
  const float var  = s2 * (1.0f / C_) - mean * mean;
  const float rstd = rsqrtf(var + 1e-5f);
  unsigned short* orow = outbf + (size_t)m * C_;
#pragma unroll
  for (int u = 0; u < 6; ++u) {
    int c = lane + 64 * u;
    orow[c] = f2bf((v[u] - mean) * rstd * g[c] + bb[c]);
  }
}

// ---------------- MFMA GEMM: C[M,N] = A[M,K](bf16) @ W[N,K]^T(f32->bf16) -----
// 128x128 tile, BK=64, 4 waves 2x2 (64x64 each, 4x4 frags of 16x16x32).
// A staged via global_load_lds w/ pre-swizzled source; B reg-staged f32->bf16
// with swizzled ds_write. XOR swizzle: chunk ^= (row&7), chunk = 16B unit.
// EPI: 0 bf16 store; 1 gelu->bf16; 2 window-reverse+unshift+resid ->f32 d_out;
//      3 d_out += val (f32)
#define BM 128
#define BN 128
#define BKg 64

template<int EPI>
__global__ __launch_bounds__(256)
void mfma_gemm(const unsigned short* __restrict__ A,   // [M,K] bf16
               const float* __restrict__ Wf,           // [N,K] f32
               const float* __restrict__ bias,
               void* __restrict__ outv,
               const float* __restrict__ resid,
               int M, int Nn, int K) {
  __shared__ unsigned short Al[BM * BKg];
  __shared__ unsigned short Bl[BN * BKg];
  const int t    = threadIdx.x;
  const int wid  = t >> 6;
  const int lane = t & 63;
  const int wr   = wid >> 1, wc = wid & 1;
  const int m0 = blockIdx.y * BM;
  const int n0 = blockIdx.x * BN;

  f32x4 acc[4][4] = {};

  // A staging geometry (per global_load_lds issue i: 32 rows, wave gets 8)
  const int sr8    = lane >> 3;                 // row within wave's 8-row group
  const int schunk = (lane & 7) ^ (sr8 & 7);    // pre-swizzled source chunk
  // B staging geometry (per pass p: 32 rows, 8 chunks/row)
  const int brow   = t >> 3;                    // 0..31
  const int bchunk = t & 7;

  const int fr  = lane & 15;        // fragment row/col index
  const int fq  = lane >> 4;        // quarter-wave -> k-chunk select

  for (int k0 = 0; k0 < K; k0 += BKg) {
    __syncthreads();
    // ---- A tile: 4 x global_load_lds (1KB per wave per issue) ----
#pragma unroll
    for (int i = 0; i < 4; ++i) {
      const int r = i * 32 + wid * 8 + sr8;
      gload_lds16(A + (size_t)(m0 + r) * K + k0 + schunk * 8,
                  (void*)(Al + (size_t)(i * 32 + wid * 8) * BKg));
    }
    // ---- B tile: reg-stage f32 weights -> bf16, swizzled ds_write ----
#pragma unroll
    for (int p = 0; p < 4; ++p) {
      const int rb = p * 32 + brow;
      const float* wp = Wf + (size_t)(n0 + rb) * K + k0 + bchunk * 8;
      const float4 w0 = *(const float4*)(wp);
      const float4 w1 = *(const float4*)(wp + 4);
      bf16x8 pv;
      pv[0] = (__bf16)w0.x; pv[1] = (__bf16)w0.y;
      pv[2] = (__bf16)w0.z; pv[3] = (__bf16)w0.w;
      pv[4] = (__bf16)w1.x; pv[5] = (__bf16)w1.y;
      pv[6] = (__bf16)w1.z; pv[7] = (__bf16)w1.w;
      const int sw = bchunk ^ (rb & 7);
      *(bf16x8*)(Bl + (size_t)rb * BKg + sw * 8) = pv;
    }
    __syncthreads();   // drains vmcnt (global_load_lds) + lgkm (ds_write)

    // ---- compute: 2 k-chunks of 32, 16 MFMA each ----
#pragma unroll
    for (int kk = 0; kk < 2; ++kk) {
      bf16x8 af[4], bfr[4];
#pragma unroll
      for (int mi = 0; mi < 4; ++mi) {
        const int row = wr * 64 + mi * 16 + fr;
        const int ch  = (kk * 4 + fq) ^ (row & 7);
        af[mi] = *(const bf16x8*)(Al + (size_t)row * BKg + ch * 8);
      }
#pragma unroll
      for (int ni = 0; ni < 4; ++ni) {
        const int row = wc * 64 + ni * 16 + fr;
        const int ch  = (kk * 4 + fq) ^ (row & 7);
        bfr[ni] = *(const bf16x8*)(Bl + (size_t)row * BKg + ch * 8);
      }
#pragma unroll
      for (int mi = 0; mi < 4; ++mi)
#pragma unroll
        for (int ni = 0; ni < 4; ++ni)
          acc[mi][ni] = __builtin_amdgcn_mfma_f32_16x16x32_bf16(
              af[mi], bfr[ni], acc[mi][ni], 0, 0, 0);
    }
  }

  // ---- epilogue: C/D layout col=lane&15, row=(lane>>4)*4+reg ----
  const int ecol  = fr;
  const int erow0 = fq * 4;
#pragma unroll
  for (int mi = 0; mi < 4; ++mi) {
#pragma unroll
    for (int r = 0; r < 4; ++r) {
      const int m = m0 + wr * 64 + mi * 16 + erow0 + r;
      size_t dstbase = 0;
      if (EPI == 2) {
        int w = m / NTOK_, tt = m - w * NTOK_;
        int bz = w >> 6, widx = w & 63;
        int wh = widx >> 3, ww = widx & 7;
        int ih = tt / WIN_, iw = tt - ih * WIN_;
        int gh = (wh * WIN_ + ih + SHIFT_) % H_;
        int gw = (ww * WIN_ + iw + SHIFT_) % W_;
        dstbase = ((size_t)bz * (H_ * W_) + gh * W_ + gw) * C_;
      }
#pragma unroll
      for (int ni = 0; ni < 4; ++ni) {
        const int n = n0 + wc * 64 + ni * 16 + ecol;
        float val = acc[mi][ni][r] + bias[n];
        if (EPI == 0) {
          ((unsigned short*)outv)[(size_t)m * Nn + n] = f2bf(val);
        } else if (EPI == 1) {
          ((unsigned short*)outv)[(size_t)m * Nn + n] = f2bf(gelu_exact(val));
        } else if (EPI == 2) {
          ((float*)outv)[dstbase + n] = resid[dstbase + n] + val;
        } else {
          float* o = (float*)outv + (size_t)m * Nn + n;
          *o += val;
        }
      }
    }
  }
}

// ---------------- Windowed attention: one block = (window, head) ------------
__global__ __launch_bounds__(64)
void attn_kernel(const unsigned short* __restrict__ qkv,   // [T_,1152] bf16
                 const float* __restrict__ rel_bias,       // [169,12]
                 unsigned short* __restrict__ out) {       // [T_,384] bf16
  __shared__ float sQ[NTOK_][HD_];
  __shared__ float sK[NTOK_][HD_];
  __shared__ float sV[NTOK_][HD_];
  __shared__ float sS[NTOK_][NTOK_];
  const int blk  = blockIdx.x;
  const int w    = blk / HEADS_;
  const int head = blk - w * HEADS_;
  const int widx = w & 63;
  const int wh   = widx >> 3, ww = widx & 7;
  const bool edge = (wh == 7) || (ww == 7);
  const int lane = threadIdx.x;
  const size_t base = (size_t)w * NTOK_ * (3 * C_);

  for (int idx = lane; idx < NTOK_ * HD_; idx += 64) {
    int i = idx >> 5, d = idx & 31;
    size_t roff = base + (size_t)i * (3 * C_) + head * HD_ + d;
    sQ[i][d] = bf2f(qkv[roff])            * 0.17677669529663687f;  // 1/sqrt(32)
    sK[i][d] = bf2f(qkv[roff + C_]);
    sV[i][d] = bf2f(qkv[roff + 2 * C_]);
  }
  __syncthreads();

  for (int idx = lane; idx < NTOK_ * NTOK_; idx += 64) {
    int i = idx / NTOK_, j = idx - i * NTOK_;
    float s = 0.f;
#pragma unroll
    for (int d = 0; d < HD_; ++d) s += sQ[i][d] * sK[j][d];
    int ih = i / WIN_, iw = i - ih * WIN_;
    int jh = j / WIN_, jw = j - jh * WIN_;
    int ridx = (ih - jh + WIN_ - 1) * (2 * WIN_ - 1) + (iw - jw + WIN_ - 1);
    s += rel_bias[ridx * HEADS_ + head];
    if (edge) {
      int shi = wh * WIN_ + ih, swi = ww * WIN_ + iw;
      int shj = wh * WIN_ + jh, swj = ww * WIN_ + jw;
      int li = (shi < 49 ? 0 : (shi < 53 ? 1 : 2)) * 3 + (swi < 49 ? 0 : (swi < 53 ? 1 : 2));
      int lj = (shj < 49 ? 0 : (shj < 53 ? 1 : 2)) * 3 + (swj < 49 ? 0 : (swj < 53 ? 1 : 2));
      if (li != lj) s -= 100.0f;
    }
    sS[i][j] = s;
  }
  __syncthreads();

  if (lane < NTOK_) {
    float mx = -1e30f;
    for (int j = 0; j < NTOK_; ++j) mx = fmaxf(mx, sS[lane][j]);
    float sum = 0.f;
    for (int j = 0; j < NTOK_; ++j) { float e = expf(sS[lane][j] - mx); sS[lane][j] = e; sum += e; }
    float inv = 1.0f / sum;
    for (int j = 0; j < NTOK_; ++j) sS[lane][j] *= inv;
  }
  __syncthreads();

  for (int idx = lane; idx < NTOK_ * HD_; idx += 64) {
    int i = idx >> 5, d = idx & 31;
    float o = 0.f;
    for (int j = 0; j < NTOK_; ++j) o += sS[i][j] * sV[j][d];
    out[(size_t)(w * NTOK_ + i) * C_ + head * HD_ + d] = f2bf(o);
  }
}

// -----------------------------------------------------------------------------
extern "C" void kernel_launch(void* const* d_in, const int* in_sizes, int n_in,
                              void* d_out, int out_size, void* d_ws, size_t ws_size,
                              hipStream_t stream) {
  const float* x        = (const float*)d_in[0];
  const float* g1       = (const float*)d_in[1];
  const float* b1       = (const float*)d_in[2];
  const float* qkv_w    = (const float*)d_in[3];
  const float* qkv_b    = (const float*)d_in[4];
  const float* rel_bias = (const float*)d_in[5];
  const float* proj_w   = (const float*)d_in[6];
  const float* proj_b   = (const float*)d_in[7];
  const float* g2       = (const float*)d_in[8];
  const float* b2       = (const float*)d_in[9];
  const float* fc1_w    = (const float*)d_in[10];
  const float* fc1_b    = (const float*)d_in[11];
  const float* fc2_w    = (const float*)d_in[12];
  const float* fc2_b    = (const float*)d_in[13];
  float* out = (float*)d_out;

  char* ws = (char*)d_ws;
  // region A [0, 77,070,336): xw -> attn_out -> h2   (T_*384 bf16)
  // region B [77,070,336, +308,281,344): qkv (T_*1152 bf16) -> hid (T_*1536 bf16)
  unsigned short* xw   = (unsigned short*)(ws);
  unsigned short* qkvb = (unsigned short*)(ws + 77070336);
  unsigned short* attn_out = xw;
  unsigned short* h2   = xw;
  unsigned short* hid  = qkvb;

  // 1. LN1 + shift + window partition -> xw (bf16, window layout)
  ln_kernel<1><<<dim3(T_), dim3(64), 0, stream>>>(x, g1, b1, xw);

  // 2. QKV GEMM: [T_,384] @ [1152,384]^T -> qkv (bf16)
  mfma_gemm<0><<<dim3(1152 / BN, T_ / BM), dim3(256), 0, stream>>>(
      xw, qkv_w, qkv_b, (void*)qkvb, nullptr, T_, 1152, 384);

  // 3. Windowed attention (bias + shift mask + softmax + PV) -> attn_out
  attn_kernel<<<dim3((T_ / NTOK_) * HEADS_), dim3(64), 0, stream>>>(qkvb, rel_bias, attn_out);

  // 4. proj GEMM + window-reverse + unshift + residual -> d_out = x1 (f32)
  mfma_gemm<2><<<dim3(384 / BN, T_ / BM), dim3(256), 0, stream>>>(
      attn_out, proj_w, proj_b, (void*)out, x, T_, 384, 384);

  // 5. LN2 on x1 -> h2 (bf16)
  ln_kernel<0><<<dim3(T_), dim3(64), 0, stream>>>(out, g2, b2, h2);

  // 6. FC1 + exact GELU -> hid (bf16)
  mfma_gemm<1><<<dim3(MLP_ / BN, T_ / BM), dim3(256), 0, stream>>>(
      h2, fc1_w, fc1_b, (void*)hid, nullptr, T_, MLP_, 384);

  // 7. FC2, d_out += result  (final = x1 + mlp)
  mfma_gemm<3><<<dim3(384 / BN, T_ / BM), dim3(256), 0, stream>>>(
      hid, fc2_w, fc2_b, (void*)out, nullptr, T_, 384, MLP_);
}

// Round 3
// 1104.104 us; speedup vs baseline: 5.0426x; 1.5745x over previous
//
#include <hip/hip_runtime.h>
#include <hip/hip_bf16.h>
#include <math.h>

#define B_      32
#define H_      56
#define W_      56
#define C_      384
#define HEADS_  12
#define WIN_    7
#define SHIFT_  3
#define NTOK_   49
#define HD_     32
#define T_      100352   // B_*H_*W_
#define MLP_    1536

typedef __bf16 bf16x8 __attribute__((ext_vector_type(8)));
typedef unsigned short u16x8 __attribute__((ext_vector_type(8)));
typedef float  f32x4  __attribute__((ext_vector_type(4)));

__device__ __forceinline__ float bf2f(unsigned short u) {
  union { unsigned int i; float f; } v; v.i = ((unsigned int)u) << 16; return v.f;
}
__device__ __forceinline__ unsigned short f2bf(float f) {
  union { float f; unsigned int i; } v; v.f = f;
  unsigned int x = v.i;
  return (unsigned short)((x + 0x7fffu + ((x >> 16) & 1u)) >> 16);
}
__device__ __forceinline__ float gelu_exact(float x) {
  return 0.5f * x * (1.0f + erff(x * 0.7071067811865475f));
}
__device__ __forceinline__ void gload_lds16(const void* g, void* l) {
  __builtin_amdgcn_global_load_lds(
      (const __attribute__((address_space(1))) void*)g,
      (__attribute__((address_space(3))) void*)l, 16, 0, 0);
}
__device__ __forceinline__ bf16x8 ldg8(const unsigned short* p) {
  u16x8 v = *(const u16x8*)p;
  return __builtin_bit_cast(bf16x8, v);
}

// ---------------- LayerNorm (optionally fused shift+window-partition remap) --
template<int REMAP>
__global__ __launch_bounds__(64)
void ln_kernel(const float* __restrict__ xin, const float* __restrict__ g,
               const float* __restrict__ bb, unsigned short* __restrict__ outbf) {
  const int m = blockIdx.x;
  const int lane = threadIdx.x;
  size_t src;
  if (REMAP) {
    int w = m / NTOK_, t = m - w * NTOK_;
    int bz = w >> 6, widx = w & 63;
    int wh = widx >> 3, ww = widx & 7;
    int ih = t / WIN_, iw = t - ih * WIN_;
    int gh = (wh * WIN_ + ih + SHIFT_) % H_;
    int gw = (ww * WIN_ + iw + SHIFT_) % W_;
    src = ((size_t)bz * (H_ * W_) + gh * W_ + gw) * C_;
  } else {
    src = (size_t)m * C_;
  }
  const float* row = xin + src;
  float v[6]; float s = 0.f, s2 = 0.f;
#pragma unroll
  for (int u = 0; u < 6; ++u) {
    v[u] = row[lane + 64 * u];
    s += v[u]; s2 += v[u] * v[u];
  }
#pragma unroll
  for (int off = 32; off; off >>= 1) {
    s  += __shfl_xor(s, off);
    s2 += __shfl_xor(s2, off);
  }
  const float mean = s * (1.0f / C_);
  const float var  = s2 * (1.0f / C_) - mean * mean;
  const float rstd = rsqrtf(var + 1e-5f);
  unsigned short* orow = outbf + (size_t)m * C_;
#pragma unroll
  for (int u = 0; u < 6; ++u) {
    int c = lane + 64 * u;
    orow[c] = f2bf((v[u] - mean) * rstd * g[c] + bb[c]);
  }
}

// ---------------- MFMA GEMM (unchanged from round 2, passing) ---------------
#define BM 128
#define BN 128
#define BKg 64

template<int EPI>
__global__ __launch_bounds__(256)
void mfma_gemm(const unsigned short* __restrict__ A,   // [M,K] bf16
               const float* __restrict__ Wf,           // [N,K] f32
               const float* __restrict__ bias,
               void* __restrict__ outv,
               const float* __restrict__ resid,
               int M, int Nn, int K) {
  __shared__ unsigned short Al[BM * BKg];
  __shared__ unsigned short Bl[BN * BKg];
  const int t    = threadIdx.x;
  const int wid  = t >> 6;
  const int lane = t & 63;
  const int wr   = wid >> 1, wc = wid & 1;
  const int m0 = blockIdx.y * BM;
  const int n0 = blockIdx.x * BN;

  f32x4 acc[4][4] = {};

  const int sr8    = lane >> 3;
  const int schunk = (lane & 7) ^ (sr8 & 7);
  const int brow   = t >> 3;
  const int bchunk = t & 7;

  const int fr  = lane & 15;
  const int fq  = lane >> 4;

  for (int k0 = 0; k0 < K; k0 += BKg) {
    __syncthreads();
#pragma unroll
    for (int i = 0; i < 4; ++i) {
      const int r = i * 32 + wid * 8 + sr8;
      gload_lds16(A + (size_t)(m0 + r) * K + k0 + schunk * 8,
                  (void*)(Al + (size_t)(i * 32 + wid * 8) * BKg));
    }
#pragma unroll
    for (int p = 0; p < 4; ++p) {
      const int rb = p * 32 + brow;
      const float* wp = Wf + (size_t)(n0 + rb) * K + k0 + bchunk * 8;
      const float4 w0 = *(const float4*)(wp);
      const float4 w1 = *(const float4*)(wp + 4);
      bf16x8 pv;
      pv[0] = (__bf16)w0.x; pv[1] = (__bf16)w0.y;
      pv[2] = (__bf16)w0.z; pv[3] = (__bf16)w0.w;
      pv[4] = (__bf16)w1.x; pv[5] = (__bf16)w1.y;
      pv[6] = (__bf16)w1.z; pv[7] = (__bf16)w1.w;
      const int sw = bchunk ^ (rb & 7);
      *(bf16x8*)(Bl + (size_t)rb * BKg + sw * 8) = pv;
    }
    __syncthreads();

#pragma unroll
    for (int kk = 0; kk < 2; ++kk) {
      bf16x8 af[4], bfr[4];
#pragma unroll
      for (int mi = 0; mi < 4; ++mi) {
        const int row = wr * 64 + mi * 16 + fr;
        const int ch  = (kk * 4 + fq) ^ (row & 7);
        af[mi] = *(const bf16x8*)(Al + (size_t)row * BKg + ch * 8);
      }
#pragma unroll
      for (int ni = 0; ni < 4; ++ni) {
        const int row = wc * 64 + ni * 16 + fr;
        const int ch  = (kk * 4 + fq) ^ (row & 7);
        bfr[ni] = *(const bf16x8*)(Bl + (size_t)row * BKg + ch * 8);
      }
#pragma unroll
      for (int mi = 0; mi < 4; ++mi)
#pragma unroll
        for (int ni = 0; ni < 4; ++ni)
          acc[mi][ni] = __builtin_amdgcn_mfma_f32_16x16x32_bf16(
              af[mi], bfr[ni], acc[mi][ni], 0, 0, 0);
    }
  }

  const int ecol  = fr;
  const int erow0 = fq * 4;
#pragma unroll
  for (int mi = 0; mi < 4; ++mi) {
#pragma unroll
    for (int r = 0; r < 4; ++r) {
      const int m = m0 + wr * 64 + mi * 16 + erow0 + r;
      size_t dstbase = 0;
      if (EPI == 2) {
        int w = m / NTOK_, tt = m - w * NTOK_;
        int bz = w >> 6, widx = w & 63;
        int wh = widx >> 3, ww = widx & 7;
        int ih = tt / WIN_, iw = tt - ih * WIN_;
        int gh = (wh * WIN_ + ih + SHIFT_) % H_;
        int gw = (ww * WIN_ + iw + SHIFT_) % W_;
        dstbase = ((size_t)bz * (H_ * W_) + gh * W_ + gw) * C_;
      }
#pragma unroll
      for (int ni = 0; ni < 4; ++ni) {
        const int n = n0 + wc * 64 + ni * 16 + ecol;
        float val = acc[mi][ni][r] + bias[n];
        if (EPI == 0) {
          ((unsigned short*)outv)[(size_t)m * Nn + n] = f2bf(val);
        } else if (EPI == 1) {
          ((unsigned short*)outv)[(size_t)m * Nn + n] = f2bf(gelu_exact(val));
        } else if (EPI == 2) {
          ((float*)outv)[dstbase + n] = resid[dstbase + n] + val;
        } else {
          float* o = (float*)outv + (size_t)m * Nn + n;
          *o += val;
        }
      }
    }
  }
}

// ---------------- bias expansion: rel_bias[169,12] -> biasx[12][49][49] -----
__global__ __launch_bounds__(64)
void bias_expand_kernel(const float* __restrict__ rel_bias,
                        float* __restrict__ biasx) {
  const int hi = blockIdx.x;              // head*49 + i
  const int head = hi / NTOK_, i = hi - head * NTOK_;
  const int j = threadIdx.x;
  if (j < NTOK_) {
    const int ih = i / 7, iw = i - ih * 7;
    const int jh = j / 7, jw = j - jh * 7;
    const int ridx = (ih - jh + 6) * 13 + (iw - jw + 6);
    biasx[(size_t)hi * NTOK_ + j] = rel_bias[ridx * HEADS_ + head];
  }
}

// ---------------- MFMA windowed attention: one wave = (window, head) --------
// 49 padded to 64. Wave-private LDS (no __syncthreads). 2 waves/block.
#define AW 2
__global__ __launch_bounds__(64 * AW)
void attn_mfma_kernel(const unsigned short* __restrict__ qkv,  // [T_,1152] bf16
                      const float* __restrict__ biasx,         // [12][49][49]
                      unsigned short* __restrict__ out) {      // [T_,384] bf16
  __shared__ unsigned short sP[AW][64 * 72];   // P  (rows=i, cols=j), stride 72
  __shared__ unsigned short sVT[AW][32 * 72];  // V^T (rows=d, cols=j), stride 72
  const int wid  = threadIdx.x >> 6;
  const int lane = threadIdx.x & 63;
  const int task = blockIdx.x * AW + wid;      // < 24576
  const int w    = task / HEADS_;
  const int head = task - w * HEADS_;
  const int widx = w & 63;
  const int wh = widx >> 3, ww = widx & 7;
  const bool edge = (wh == 7) || (ww == 7);
  const int c  = lane & 15;    // fragment col / A-row
  const int fq = lane >> 4;    // lane quarter
  unsigned short* Pl = sP[wid];
  unsigned short* Vl = sVT[wid];
  const unsigned short* qw = qkv + (size_t)w * NTOK_ * (3 * C_);

  // ---- early V loads: j = p*16+c, d-octet = fq ----
  u16x8 vv[4];
#pragma unroll
  for (int p = 0; p < 4; ++p)
    vv[p] = *(const u16x8*)(qw + (size_t)(p * 16 + c) * (3 * C_) + 2 * C_ + head * HD_ + fq * 8);

  // ---- Q as A-frags (row=c+16mi, k=d=fq*8..), K as B-frags (col=c+16ni) ----
  bf16x8 aQ[4], bK[4];
#pragma unroll
  for (int mi = 0; mi < 4; ++mi)
    aQ[mi] = ldg8(qw + (size_t)(mi * 16 + c) * (3 * C_) + head * HD_ + fq * 8);
#pragma unroll
  for (int ni = 0; ni < 4; ++ni)
    bK[ni] = ldg8(qw + (size_t)(ni * 16 + c) * (3 * C_) + C_ + head * HD_ + fq * 8);

  // ---- S = Q K^T : 16 MFMAs, K=32 in one shot ----
  const f32x4 zero4 = {0.f, 0.f, 0.f, 0.f};
  f32x4 accS[4][4];
#pragma unroll
  for (int mi = 0; mi < 4; ++mi)
#pragma unroll
    for (int ni = 0; ni < 4; ++ni)
      accS[mi][ni] = __builtin_amdgcn_mfma_f32_16x16x32_bf16(aQ[mi], bK[ni], zero4, 0, 0, 0);

  // ---- V^T into wave-private LDS ----
#pragma unroll
  for (int p = 0; p < 4; ++p)
#pragma unroll
    for (int u = 0; u < 8; ++u)
      Vl[(fq * 8 + u) * 72 + p * 16 + c] = (unsigned short)vv[p][u];

  // ---- softmax over j (per-row); bias from expanded table; analytic mask ----
  float rowinv[4][4];
  const float* bh = biasx + (size_t)head * (NTOK_ * NTOK_);
#pragma unroll
  for (int mi = 0; mi < 4; ++mi) {
#pragma unroll
    for (int r = 0; r < 4; ++r) {
      const int i  = mi * 16 + fq * 4 + r;          // S row
      const int ic = i < NTOK_ ? i : 0;
      const int ih = ic / 7, iw = ic - ih * 7;
      int li = 0;
      if (edge) {
        const int shi = wh * 7 + ih, swi = ww * 7 + iw;
        li = (shi < 49 ? 0 : (shi < 53 ? 1 : 2)) * 3 + (swi < 49 ? 0 : (swi < 53 ? 1 : 2));
      }
      float sv[4];
#pragma unroll
      for (int ni = 0; ni < 4; ++ni) {
        const int j  = ni * 16 + c;
        const int jc = j < NTOK_ ? j : 0;
        float s = accS[mi][ni][r] * 0.17677669529663687f + bh[ic * NTOK_ + jc];
        if (edge) {
          const int jh = jc / 7, jw = jc - jh * 7;
          const int shj = wh * 7 + jh, swj = ww * 7 + jw;
          const int lj = (shj < 49 ? 0 : (shj < 53 ? 1 : 2)) * 3 + (swj < 49 ? 0 : (swj < 53 ? 1 : 2));
          if (lj != li) s -= 100.f;
        }
        if (j >= NTOK_) s = -1e30f;
        sv[ni] = s;
      }
      float mx = fmaxf(fmaxf(sv[0], sv[1]), fmaxf(sv[2], sv[3]));
      mx = fmaxf(mx, __shfl_xor(mx, 1));
      mx = fmaxf(mx, __shfl_xor(mx, 2));
      mx = fmaxf(mx, __shfl_xor(mx, 4));
      mx = fmaxf(mx, __shfl_xor(mx, 8));
      const float e0 = __expf(sv[0] - mx), e1 = __expf(sv[1] - mx);
      const float e2 = __expf(sv[2] - mx), e3 = __expf(sv[3] - mx);
      float sm = e0 + e1 + e2 + e3;
      sm += __shfl_xor(sm, 1);
      sm += __shfl_xor(sm, 2);
      sm += __shfl_xor(sm, 4);
      sm += __shfl_xor(sm, 8);
      rowinv[mi][r] = 1.0f / sm;           // >= 1 element e^0 -> never 0
      const int prow = i * 72;
      Pl[prow +  0 + c] = f2bf(e0);        // unnormalized; O scaled by rowinv
      Pl[prow + 16 + c] = f2bf(e1);
      Pl[prow + 32 + c] = f2bf(e2);
      Pl[prow + 48 + c] = f2bf(e3);
    }
  }

  // ---- O = P V : A = P rows (b128 from LDS), B = V^T rows (b128 from LDS) ----
  f32x4 accO[4][2] = {};
#pragma unroll
  for (int kk = 0; kk < 2; ++kk) {
    bf16x8 ap[4], bv[2];
#pragma unroll
    for (int mi = 0; mi < 4; ++mi)
      ap[mi] = __builtin_bit_cast(bf16x8,
          *(const u16x8*)(Pl + (mi * 16 + c) * 72 + kk * 32 + fq * 8));
#pragma unroll
    for (int nd = 0; nd < 2; ++nd)
      bv[nd] = __builtin_bit_cast(bf16x8,
          *(const u16x8*)(Vl + (nd * 16 + c) * 72 + kk * 32 + fq * 8));
#pragma unroll
    for (int mi = 0; mi < 4; ++mi)
#pragma unroll
      for (int nd = 0; nd < 2; ++nd)
        accO[mi][nd] = __builtin_amdgcn_mfma_f32_16x16x32_bf16(ap[mi], bv[nd], accO[mi][nd], 0, 0, 0);
  }

  // ---- store O rows < 49, scaled by 1/rowsum ----
#pragma unroll
  for (int mi = 0; mi < 4; ++mi)
#pragma unroll
    for (int r = 0; r < 4; ++r) {
      const int i = mi * 16 + fq * 4 + r;
      if (i < NTOK_) {
        const float inv = rowinv[mi][r];
#pragma unroll
        for (int nd = 0; nd < 2; ++nd)
          out[(size_t)(w * NTOK_ + i) * C_ + head * HD_ + nd * 16 + c] =
              f2bf(accO[mi][nd][r] * inv);
      }
    }
}

// -----------------------------------------------------------------------------
extern "C" void kernel_launch(void* const* d_in, const int* in_sizes, int n_in,
                              void* d_out, int out_size, void* d_ws, size_t ws_size,
                              hipStream_t stream) {
  const float* x        = (const float*)d_in[0];
  const float* g1       = (const float*)d_in[1];
  const float* b1       = (const float*)d_in[2];
  const float* qkv_w    = (const float*)d_in[3];
  const float* qkv_b    = (const float*)d_in[4];
  const float* rel_bias = (const float*)d_in[5];
  const float* proj_w   = (const float*)d_in[6];
  const float* proj_b   = (const float*)d_in[7];
  const float* g2       = (const float*)d_in[8];
  const float* b2       = (const float*)d_in[9];
  const float* fc1_w    = (const float*)d_in[10];
  const float* fc1_b    = (const float*)d_in[11];
  const float* fc2_w    = (const float*)d_in[12];
  const float* fc2_b    = (const float*)d_in[13];
  float* out = (float*)d_out;

  char* ws = (char*)d_ws;
  // region A [0, 77,070,336): xw -> attn_out -> h2   (T_*384 bf16)
  // region B [77,070,336, +308,281,344): qkv (T_*1152 bf16) -> hid (T_*1536 bf16)
  // biasx: 115 KB parked 128 KB past qkv end (inside hid region; hid is written
  // only after attention has consumed biasx, and rewritten every replay).
  unsigned short* xw   = (unsigned short*)(ws);
  unsigned short* qkvb = (unsigned short*)(ws + 77070336);
  unsigned short* attn_out = xw;
  unsigned short* h2   = xw;
  unsigned short* hid  = qkvb;
  float* biasx = (float*)(ws + 308412416);

  // 0. rel-pos bias expansion -> biasx[12][49][49]
  bias_expand_kernel<<<dim3(HEADS_ * NTOK_), dim3(64), 0, stream>>>(rel_bias, biasx);

  // 1. LN1 + shift + window partition -> xw (bf16, window layout)
  ln_kernel<1><<<dim3(T_), dim3(64), 0, stream>>>(x, g1, b1, xw);

  // 2. QKV GEMM: [T_,384] @ [1152,384]^T -> qkv (bf16)
  mfma_gemm<0><<<dim3(1152 / BN, T_ / BM), dim3(256), 0, stream>>>(
      xw, qkv_w, qkv_b, (void*)qkvb, nullptr, T_, 1152, 384);

  // 3. MFMA windowed attention -> attn_out
  attn_mfma_kernel<<<dim3((T_ / NTOK_) * HEADS_ / AW), dim3(64 * AW), 0, stream>>>(
      qkvb, biasx, attn_out);

  // 4. proj GEMM + window-reverse + unshift + residual -> d_out = x1 (f32)
  mfma_gemm<2><<<dim3(384 / BN, T_ / BM), dim3(256), 0, stream>>>(
      attn_out, proj_w, proj_b, (void*)out, x, T_, 384, 384);

  // 5. LN2 on x1 -> h2 (bf16)
  ln_kernel<0><<<dim3(T_), dim3(64), 0, stream>>>(out, g2, b2, h2);

  // 6. FC1 + exact GELU -> hid (bf16)
  mfma_gemm<1><<<dim3(MLP_ / BN, T_ / BM), dim3(256), 0, stream>>>(
      h2, fc1_w, fc1_b, (void*)hid, nullptr, T_, MLP_, 384);

  // 7. FC2, d_out += result  (final = x1 + mlp)
  mfma_gemm<3><<<dim3(384 / BN, T_ / BM), dim3(256), 0, stream>>>(
      hid, fc2_w, fc2_b, (void*)out, nullptr, T_, 384, MLP_);
}

// Round 4
// 1035.933 us; speedup vs baseline: 5.3745x; 1.0658x over previous
//
#include <hip/hip_runtime.h>
#include <hip/hip_bf16.h>
#include <math.h>

#define B_      32
#define H_      56
#define W_      56
#define C_      384
#define HEADS_  12
#define WIN_    7
#define SHIFT_  3
#define NTOK_   49
#define HD_     32
#define T_      100352   // B_*H_*W_
#define MLP_    1536

typedef __bf16 bf16x8 __attribute__((ext_vector_type(8)));
typedef unsigned short u16x8 __attribute__((ext_vector_type(8)));
typedef float  f32x4  __attribute__((ext_vector_type(4)));

__device__ __forceinline__ float bf2f(unsigned short u) {
  union { unsigned int i; float f; } v; v.i = ((unsigned int)u) << 16; return v.f;
}
__device__ __forceinline__ unsigned short f2bf(float f) {
  union { float f; unsigned int i; } v; v.f = f;
  unsigned int x = v.i;
  return (unsigned short)((x + 0x7fffu + ((x >> 16) & 1u)) >> 16);
}
__device__ __forceinline__ float gelu_exact(float x) {
  return 0.5f * x * (1.0f + erff(x * 0.7071067811865475f));
}
__device__ __forceinline__ void gload_lds16(const void* g, void* l) {
  __builtin_amdgcn_global_load_lds(
      (const __attribute__((address_space(1))) void*)g,
      (__attribute__((address_space(3))) void*)l, 16, 0, 0);
}
__device__ __forceinline__ bf16x8 ldg8(const unsigned short* p) {
  u16x8 v = *(const u16x8*)p;
  return __builtin_bit_cast(bf16x8, v);
}

// ---------------- f32 -> bf16 weight convert (n divisible by 1024) ----------
__global__ __launch_bounds__(256)
void wconv_kernel(const float* __restrict__ src, unsigned short* __restrict__ dst, int n) {
  const int i = (blockIdx.x * 256 + threadIdx.x) * 4;
  if (i < n) {
    const float4 v = *(const float4*)(src + i);
    ushort4 o;
    o.x = f2bf(v.x); o.y = f2bf(v.y); o.z = f2bf(v.z); o.w = f2bf(v.w);
    *(ushort4*)(dst + i) = o;
  }
}

// ---------------- LayerNorm: 4 rows / 256-thread block ----------------------
template<int REMAP>
__global__ __launch_bounds__(256)
void ln_kernel(const float* __restrict__ xin, const float* __restrict__ g,
               const float* __restrict__ bb, unsigned short* __restrict__ outbf) {
  const int m = blockIdx.x * 4 + (threadIdx.x >> 6);
  const int lane = threadIdx.x & 63;
  size_t src;
  if (REMAP) {
    int w = m / NTOK_, t = m - w * NTOK_;
    int bz = w >> 6, widx = w & 63;
    int wh = widx >> 3, ww = widx & 7;
    int ih = t / WIN_, iw = t - ih * WIN_;
    int gh = (wh * WIN_ + ih + SHIFT_) % H_;
    int gw = (ww * WIN_ + iw + SHIFT_) % W_;
    src = ((size_t)bz * (H_ * W_) + gh * W_ + gw) * C_;
  } else {
    src = (size_t)m * C_;
  }
  const float* row = xin + src;
  float v[6]; float s = 0.f, s2 = 0.f;
#pragma unroll
  for (int u = 0; u < 6; ++u) {
    v[u] = row[lane + 64 * u];
    s += v[u]; s2 += v[u] * v[u];
  }
#pragma unroll
  for (int off = 32; off; off >>= 1) {
    s  += __shfl_xor(s, off);
    s2 += __shfl_xor(s2, off);
  }
  const float mean = s * (1.0f / C_);
  const float var  = s2 * (1.0f / C_) - mean * mean;
  const float rstd = rsqrtf(var + 1e-5f);
  unsigned short* orow = outbf + (size_t)m * C_;
#pragma unroll
  for (int u = 0; u < 6; ++u) {
    int c = lane + 64 * u;
    orow[c] = f2bf((v[u] - mean) * rstd * g[c] + bb[c]);
  }
}

// ---------------- MFMA GEMM: C[M,N] = A[M,K](bf16) @ W[N,K]^T + bias --------
// 128x128 tile, BK=64, 4 waves 2x2. A (and B when BSRC=1) staged via
// global_load_lds w/ pre-swizzled source; BSRC=0 reg-stages f32->bf16.
// XCD-chunked bijective blockIdx swizzle (nb divisible by 8).
// EPI: 0 bf16; 1 gelu->bf16; 2 window-reverse+unshift+resid ->f32; 3 f32 +=
#define BM 128
#define BN 128
#define BKg 64

template<int EPI, int BSRC>
__global__ __launch_bounds__(256)
void mfma_gemm(const unsigned short* __restrict__ A,   // [M,K] bf16
               const void* __restrict__ Wv,            // [N,K] f32 or bf16
               const float* __restrict__ bias,
               void* __restrict__ outv,
               const float* __restrict__ resid,
               int M, int Nn, int K) {
  __shared__ unsigned short Al[BM * BKg];
  __shared__ unsigned short Bl[BN * BKg];
  const int t    = threadIdx.x;
  const int wid  = t >> 6;
  const int lane = t & 63;
  const int wr   = wid >> 1, wc = wid & 1;

  // XCD-chunked swizzle: give each XCD a contiguous run of linear block ids.
  const unsigned int nb = gridDim.x * gridDim.y;
  unsigned int lin = blockIdx.y * gridDim.x + blockIdx.x;
  lin = (lin & 7) * (nb >> 3) + (lin >> 3);
  const int m0 = (int)(lin / gridDim.x) * BM;
  const int n0 = (int)(lin % gridDim.x) * BN;

  f32x4 acc[4][4] = {};

  const int sr8    = lane >> 3;
  const int schunk = (lane & 7) ^ (sr8 & 7);
  const int brow   = t >> 3;
  const int bchunk = t & 7;

  const int fr  = lane & 15;
  const int fq  = lane >> 4;

  for (int k0 = 0; k0 < K; k0 += BKg) {
    __syncthreads();
#pragma unroll
    for (int i = 0; i < 4; ++i) {
      const int r = i * 32 + wid * 8 + sr8;
      gload_lds16(A + (size_t)(m0 + r) * K + k0 + schunk * 8,
                  (void*)(Al + (size_t)(i * 32 + wid * 8) * BKg));
    }
    if (BSRC == 1) {
      const unsigned short* Wb = (const unsigned short*)Wv;
#pragma unroll
      for (int i = 0; i < 4; ++i) {
        const int r = i * 32 + wid * 8 + sr8;
        gload_lds16(Wb + (size_t)(n0 + r) * K + k0 + schunk * 8,
                    (void*)(Bl + (size_t)(i * 32 + wid * 8) * BKg));
      }
    } else {
      const float* Wf = (const float*)Wv;
#pragma unroll
      for (int p = 0; p < 4; ++p) {
        const int rb = p * 32 + brow;
        const float* wp = Wf + (size_t)(n0 + rb) * K + k0 + bchunk * 8;
        const float4 w0 = *(const float4*)(wp);
        const float4 w1 = *(const float4*)(wp + 4);
        bf16x8 pv;
        pv[0] = (__bf16)w0.x; pv[1] = (__bf16)w0.y;
        pv[2] = (__bf16)w0.z; pv[3] = (__bf16)w0.w;
        pv[4] = (__bf16)w1.x; pv[5] = (__bf16)w1.y;
        pv[6] = (__bf16)w1.z; pv[7] = (__bf16)w1.w;
        const int sw = bchunk ^ (rb & 7);
        *(bf16x8*)(Bl + (size_t)rb * BKg + sw * 8) = pv;
      }
    }
    __syncthreads();

#pragma unroll
    for (int kk = 0; kk < 2; ++kk) {
      bf16x8 af[4], bfr[4];
#pragma unroll
      for (int mi = 0; mi < 4; ++mi) {
        const int row = wr * 64 + mi * 16 + fr;
        const int ch  = (kk * 4 + fq) ^ (row & 7);
        af[mi] = *(const bf16x8*)(Al + (size_t)row * BKg + ch * 8);
      }
#pragma unroll
      for (int ni = 0; ni < 4; ++ni) {
        const int row = wc * 64 + ni * 16 + fr;
        const int ch  = (kk * 4 + fq) ^ (row & 7);
        bfr[ni] = *(const bf16x8*)(Bl + (size_t)row * BKg + ch * 8);
      }
#pragma unroll
      for (int mi = 0; mi < 4; ++mi)
#pragma unroll
        for (int ni = 0; ni < 4; ++ni)
          acc[mi][ni] = __builtin_amdgcn_mfma_f32_16x16x32_bf16(
              af[mi], bfr[ni], acc[mi][ni], 0, 0, 0);
    }
  }

  const int ecol  = fr;
  const int erow0 = fq * 4;
#pragma unroll
  for (int mi = 0; mi < 4; ++mi) {
#pragma unroll
    for (int r = 0; r < 4; ++r) {
      const int m = m0 + wr * 64 + mi * 16 + erow0 + r;
      size_t dstbase = 0;
      if (EPI == 2) {
        int w = m / NTOK_, tt = m - w * NTOK_;
        int bz = w >> 6, widx = w & 63;
        int wh = widx >> 3, ww = widx & 7;
        int ih = tt / WIN_, iw = tt - ih * WIN_;
        int gh = (wh * WIN_ + ih + SHIFT_) % H_;
        int gw = (ww * WIN_ + iw + SHIFT_) % W_;
        dstbase = ((size_t)bz * (H_ * W_) + gh * W_ + gw) * C_;
      }
#pragma unroll
      for (int ni = 0; ni < 4; ++ni) {
        const int n = n0 + wc * 64 + ni * 16 + ecol;
        float val = acc[mi][ni][r] + bias[n];
        if (EPI == 0) {
          ((unsigned short*)outv)[(size_t)m * Nn + n] = f2bf(val);
        } else if (EPI == 1) {
          ((unsigned short*)outv)[(size_t)m * Nn + n] = f2bf(gelu_exact(val));
        } else if (EPI == 2) {
          ((float*)outv)[dstbase + n] = resid[dstbase + n] + val;
        } else {
          float* o = (float*)outv + (size_t)m * Nn + n;
          *o += val;
        }
      }
    }
  }
}

// ---------------- bias expansion: rel_bias[169,12] -> biasx[12][49][49] -----
__global__ __launch_bounds__(64)
void bias_expand_kernel(const float* __restrict__ rel_bias,
                        float* __restrict__ biasx) {
  const int hi = blockIdx.x;              // head*49 + i
  const int head = hi / NTOK_, i = hi - head * NTOK_;
  const int j = threadIdx.x;
  if (j < NTOK_) {
    const int ih = i / 7, iw = i - ih * 7;
    const int jh = j / 7, jw = j - jh * 7;
    const int ridx = (ih - jh + 6) * 13 + (iw - jw + 6);
    biasx[(size_t)hi * NTOK_ + j] = rel_bias[ridx * HEADS_ + head];
  }
}

// ---------------- MFMA windowed attention: one wave = (window, head) --------
#define AW 2
__global__ __launch_bounds__(64 * AW)
void attn_mfma_kernel(const unsigned short* __restrict__ qkv,  // [T_,1152] bf16
                      const float* __restrict__ biasx,         // [12][49][49]
                      unsigned short* __restrict__ out) {      // [T_,384] bf16
  __shared__ unsigned short sP[AW][64 * 72];   // P  (rows=i, cols=j), stride 72
  __shared__ unsigned short sVT[AW][32 * 72];  // V^T (rows=d, cols=j), stride 72
  const int wid  = threadIdx.x >> 6;
  const int lane = threadIdx.x & 63;
  const int task = blockIdx.x * AW + wid;      // < 24576
  const int w    = task / HEADS_;
  const int head = task - w * HEADS_;
  const int widx = w & 63;
  const int wh = widx >> 3, ww = widx & 7;
  const bool edge = (wh == 7) || (ww == 7);
  const int c  = lane & 15;
  const int fq = lane >> 4;
  unsigned short* Pl = sP[wid];
  unsigned short* Vl = sVT[wid];
  const unsigned short* qw = qkv + (size_t)w * NTOK_ * (3 * C_);

  u16x8 vv[4];
#pragma unroll
  for (int p = 0; p < 4; ++p)
    vv[p] = *(const u16x8*)(qw + (size_t)(p * 16 + c) * (3 * C_) + 2 * C_ + head * HD_ + fq * 8);

  bf16x8 aQ[4], bK[4];
#pragma unroll
  for (int mi = 0; mi < 4; ++mi)
    aQ[mi] = ldg8(qw + (size_t)(mi * 16 + c) * (3 * C_) + head * HD_ + fq * 8);
#pragma unroll
  for (int ni = 0; ni < 4; ++ni)
    bK[ni] = ldg8(qw + (size_t)(ni * 16 + c) * (3 * C_) + C_ + head * HD_ + fq * 8);

  const f32x4 zero4 = {0.f, 0.f, 0.f, 0.f};
  f32x4 accS[4][4];
#pragma unroll
  for (int mi = 0; mi < 4; ++mi)
#pragma unroll
    for (int ni = 0; ni < 4; ++ni)
      accS[mi][ni] = __builtin_amdgcn_mfma_f32_16x16x32_bf16(aQ[mi], bK[ni], zero4, 0, 0, 0);

#pragma unroll
  for (int p = 0; p < 4; ++p)
#pragma unroll
    for (int u = 0; u < 8; ++u)
      Vl[(fq * 8 + u) * 72 + p * 16 + c] = (unsigned short)vv[p][u];

  float rowinv[4][4];
  const float* bh = biasx + (size_t)head * (NTOK_ * NTOK_);
#pragma unroll
  for (int mi = 0; mi < 4; ++mi) {
#pragma unroll
    for (int r = 0; r < 4; ++r) {
      const int i  = mi * 16 + fq * 4 + r;
      const int ic = i < NTOK_ ? i : 0;
      const int ih = ic / 7, iw = ic - ih * 7;
      int li = 0;
      if (edge) {
        const int shi = wh * 7 + ih, swi = ww * 7 + iw;
        li = (shi < 49 ? 0 : (shi < 53 ? 1 : 2)) * 3 + (swi < 49 ? 0 : (swi < 53 ? 1 : 2));
      }
      float sv[4];
#pragma unroll
      for (int ni = 0; ni < 4; ++ni) {
        const int j  = ni * 16 + c;
        const int jc = j < NTOK_ ? j : 0;
        float s = accS[mi][ni][r] * 0.17677669529663687f + bh[ic * NTOK_ + jc];
        if (edge) {
          const int jh = jc / 7, jw = jc - jh * 7;
          const int shj = wh * 7 + jh, swj = ww * 7 + jw;
          const int lj = (shj < 49 ? 0 : (shj < 53 ? 1 : 2)) * 3 + (swj < 49 ? 0 : (swj < 53 ? 1 : 2));
          if (lj != li) s -= 100.f;
        }
        if (j >= NTOK_) s = -1e30f;
        sv[ni] = s;
      }
      float mx = fmaxf(fmaxf(sv[0], sv[1]), fmaxf(sv[2], sv[3]));
      mx = fmaxf(mx, __shfl_xor(mx, 1));
      mx = fmaxf(mx, __shfl_xor(mx, 2));
      mx = fmaxf(mx, __shfl_xor(mx, 4));
      mx = fmaxf(mx, __shfl_xor(mx, 8));
      const float e0 = __expf(sv[0] - mx), e1 = __expf(sv[1] - mx);
      const float e2 = __expf(sv[2] - mx), e3 = __expf(sv[3] - mx);
      float sm = e0 + e1 + e2 + e3;
      sm += __shfl_xor(sm, 1);
      sm += __shfl_xor(sm, 2);
      sm += __shfl_xor(sm, 4);
      sm += __shfl_xor(sm, 8);
      rowinv[mi][r] = 1.0f / sm;
      const int prow = i * 72;
      Pl[prow +  0 + c] = f2bf(e0);
      Pl[prow + 16 + c] = f2bf(e1);
      Pl[prow + 32 + c] = f2bf(e2);
      Pl[prow + 48 + c] = f2bf(e3);
    }
  }

  f32x4 accO[4][2] = {};
#pragma unroll
  for (int kk = 0; kk < 2; ++kk) {
    bf16x8 ap[4], bv[2];
#pragma unroll
    for (int mi = 0; mi < 4; ++mi)
      ap[mi] = __builtin_bit_cast(bf16x8,
          *(const u16x8*)(Pl + (mi * 16 + c) * 72 + kk * 32 + fq * 8));
#pragma unroll
    for (int nd = 0; nd < 2; ++nd)
      bv[nd] = __builtin_bit_cast(bf16x8,
          *(const u16x8*)(Vl + (nd * 16 + c) * 72 + kk * 32 + fq * 8));
#pragma unroll
    for (int mi = 0; mi < 4; ++mi)
#pragma unroll
      for (int nd = 0; nd < 2; ++nd)
        accO[mi][nd] = __builtin_amdgcn_mfma_f32_16x16x32_bf16(ap[mi], bv[nd], accO[mi][nd], 0, 0, 0);
  }

#pragma unroll
  for (int mi = 0; mi < 4; ++mi)
#pragma unroll
    for (int r = 0; r < 4; ++r) {
      const int i = mi * 16 + fq * 4 + r;
      if (i < NTOK_) {
        const float inv = rowinv[mi][r];
#pragma unroll
        for (int nd = 0; nd < 2; ++nd)
          out[(size_t)(w * NTOK_ + i) * C_ + head * HD_ + nd * 16 + c] =
              f2bf(accO[mi][nd][r] * inv);
      }
    }
}

// -----------------------------------------------------------------------------
extern "C" void kernel_launch(void* const* d_in, const int* in_sizes, int n_in,
                              void* d_out, int out_size, void* d_ws, size_t ws_size,
                              hipStream_t stream) {
  const float* x        = (const float*)d_in[0];
  const float* g1       = (const float*)d_in[1];
  const float* b1       = (const float*)d_in[2];
  const float* qkv_w    = (const float*)d_in[3];
  const float* qkv_b    = (const float*)d_in[4];
  const float* rel_bias = (const float*)d_in[5];
  const float* proj_w   = (const float*)d_in[6];
  const float* proj_b   = (const float*)d_in[7];
  const float* g2       = (const float*)d_in[8];
  const float* b2       = (const float*)d_in[9];
  const float* fc1_w    = (const float*)d_in[10];
  const float* fc1_b    = (const float*)d_in[11];
  const float* fc2_w    = (const float*)d_in[12];
  const float* fc2_b    = (const float*)d_in[13];
  float* out = (float*)d_out;

  char* ws = (char*)d_ws;
  // region A [0, 77,070,336): xw -> attn_out -> h2 -> fc2_wb(1.18MB, post-FC1)
  // region B [77,070,336, 385,351,680): qkv (231 MB) -> hid (308 MB)
  // dead-zone (post-qkv, pre-FC1 only): qkv_wb, proj_wb, biasx at 308,412,416+
  unsigned short* xw   = (unsigned short*)(ws);
  unsigned short* qkvb = (unsigned short*)(ws + 77070336);
  unsigned short* attn_out = xw;
  unsigned short* h2   = xw;
  unsigned short* hid  = qkvb;
  unsigned short* fc2_wb  = (unsigned short*)(ws);             // region A, post-FC1
  unsigned short* qkv_wb  = (unsigned short*)(ws + 308412416); // 884,736 B
  unsigned short* proj_wb = (unsigned short*)(ws + 309297152); // 294,912 B
  float*          biasx   = (float*)(ws + 309592064);          // 115,248 B

  // 0. weight converts (qkv/proj) + bias expansion (all consumed pre-FC1)
  wconv_kernel<<<dim3(432), dim3(256), 0, stream>>>(qkv_w, qkv_wb, 3 * C_ * C_);
  wconv_kernel<<<dim3(144), dim3(256), 0, stream>>>(proj_w, proj_wb, C_ * C_);
  bias_expand_kernel<<<dim3(HEADS_ * NTOK_), dim3(64), 0, stream>>>(rel_bias, biasx);

  // 1. LN1 + shift + window partition -> xw (bf16, window layout)
  ln_kernel<1><<<dim3(T_ / 4), dim3(256), 0, stream>>>(x, g1, b1, xw);

  // 2. QKV GEMM: [T_,384] @ [1152,384]^T -> qkv (bf16)
  mfma_gemm<0, 1><<<dim3(1152 / BN, T_ / BM), dim3(256), 0, stream>>>(
      xw, qkv_wb, qkv_b, (void*)qkvb, nullptr, T_, 1152, 384);

  // 3. MFMA windowed attention -> attn_out
  attn_mfma_kernel<<<dim3((T_ / NTOK_) * HEADS_ / AW), dim3(64 * AW), 0, stream>>>(
      qkvb, biasx, attn_out);

  // 4. proj GEMM + window-reverse + unshift + residual -> d_out = x1 (f32)
  mfma_gemm<2, 1><<<dim3(384 / BN, T_ / BM), dim3(256), 0, stream>>>(
      attn_out, proj_wb, proj_b, (void*)out, x, T_, 384, 384);

  // 5. LN2 on x1 -> h2 (bf16)
  ln_kernel<0><<<dim3(T_ / 4), dim3(256), 0, stream>>>(out, g2, b2, h2);

  // 6. FC1 + exact GELU -> hid (bf16); keeps in-kernel f32 weight convert
  mfma_gemm<1, 0><<<dim3(MLP_ / BN, T_ / BM), dim3(256), 0, stream>>>(
      h2, fc1_w, fc1_b, (void*)hid, nullptr, T_, MLP_, 384);

  // 6b. convert fc2_w -> bf16 into region A (h2 fully consumed by FC1)
  wconv_kernel<<<dim3(576), dim3(256), 0, stream>>>(fc2_w, fc2_wb, C_ * MLP_);

  // 7. FC2, d_out += result  (final = x1 + mlp)
  mfma_gemm<3, 1><<<dim3(384 / BN, T_ / BM), dim3(256), 0, stream>>>(
      hid, fc2_wb, fc2_b, (void*)out, nullptr, T_, 384, MLP_);
}